// Round 1
// baseline (303.037 us; speedup 1.0000x reference)
//
#include <hip/hip_runtime.h>
#include <math.h>

// Problem: B=16, LQ=1024, LK=1024, DK=256, DV=256, fp32 in/out, mask int32.
// Key identity: softmax_k(q_s + k_s with mask) == mask-weighted softmax of k_s alone
// (q_s cancels; masked entries are exactly -1e9 -> weight 0). query is never read.

#define NB   16
#define NL   1024     // LQ == LK
#define ND   256      // DK == DV

// ---------------- Kernel A: ks[b,k] = dot(key[b,k,:], w) -----------------
// One wave per key row: 64 lanes x float4 = 256 elements, shuffle-reduce.
__global__ __launch_bounds__(256)
void ks_kernel(const float* __restrict__ key, const float* __restrict__ w,
               float* __restrict__ ks) {
    int wid  = threadIdx.x >> 6;
    int lane = threadIdx.x & 63;
    int row  = blockIdx.x * 4 + wid;               // 0 .. NB*NL-1
    const float4* krow = (const float4*)(key + (size_t)row * ND);
    float4 kv = krow[lane];
    float4 wv = ((const float4*)w)[lane];
    float p = kv.x * wv.x + kv.y * wv.y + kv.z * wv.z + kv.w * wv.w;
    #pragma unroll
    for (int off = 32; off > 0; off >>= 1)
        p += __shfl_xor(p, off, 64);
    if (lane == 0) ks[row] = p;
}

// ------- Kernel B: per batch: max, e=exp(ks-m), bitonic sort desc, -------
// ------- suffix sums rem[i] = sum_{j>i} e_sorted[j]                -------
__global__ __launch_bounds__(1024)
void sort_kernel(const float* __restrict__ ks,
                 float* __restrict__ e_s, int* __restrict__ idx_s,
                 float* __restrict__ rem) {
    __shared__ float sv[NL];
    __shared__ int   si[NL];
    __shared__ float red[NL];
    int b = blockIdx.x;
    int t = threadIdx.x;

    float v = ks[b * NL + t];
    red[t] = v;
    __syncthreads();
    for (int off = 512; off > 0; off >>= 1) {
        if (t < off) red[t] = fmaxf(red[t], red[t + off]);
        __syncthreads();
    }
    float m = red[0];
    __syncthreads();

    float e = __expf(v - m);        // e in (0,1], batch max -> e_max = 1
    sv[t] = e;
    si[t] = t;
    __syncthreads();

    // bitonic sort, descending by sv
    for (int kk = 2; kk <= NL; kk <<= 1) {
        for (int j = kk >> 1; j > 0; j >>= 1) {
            int ixj = t ^ j;
            if (ixj > t) {
                bool up = ((t & kk) == 0);          // descending overall
                float a = sv[t], c = sv[ixj];
                bool sw = up ? (a < c) : (a > c);
                if (sw) {
                    int ia = si[t];
                    sv[t] = c;  sv[ixj] = a;
                    si[t] = si[ixj]; si[ixj] = ia;
                }
            }
            __syncthreads();
        }
    }

    // inclusive suffix sum in red (Hillis-Steele), then rem = rs - self
    red[t] = sv[t];
    __syncthreads();
    for (int off = 1; off < NL; off <<= 1) {
        float add = (t + off < NL) ? red[t + off] : 0.0f;
        __syncthreads();
        red[t] += add;
        __syncthreads();
    }
    e_s  [b * NL + t] = sv[t];
    idx_s[b * NL + t] = si[t];
    rem  [b * NL + t] = red[t] - sv[t];   // >= 0 (fl(a+b) >= a for b>=0)
}

// ---------------- Kernel C: out[b,q,:] = sum_k p * value[b,k,:] ----------
// One wave per (b,q) row. Walk sorted-e list; stop when provable remaining
// mass rem[i] <= 1e-6 * Zhat. Error bound ~1e-5 << 9.3e-2 threshold.
__global__ __launch_bounds__(256)
void attn_kernel(const float* __restrict__ value, const int* __restrict__ mask,
                 const float* __restrict__ e_s, const int* __restrict__ idx_s,
                 const float* __restrict__ rem, float* __restrict__ out) {
    int wid  = threadIdx.x >> 6;
    int lane = threadIdx.x & 63;
    int row  = blockIdx.x * 4 + wid;      // 0 .. NB*NL-1
    int b    = row >> 10;
    const int base = b << 10;
    const int*    mrow  = mask + (size_t)row * NL;
    const float4* vbase = (const float4*)(value + ((size_t)b << 10) * ND);

    float4 acc = make_float4(0.f, 0.f, 0.f, 0.f);
    float Z = 0.0f;

    for (int i = 0; i < NL; ++i) {
        int   k  = idx_s[base + i];
        float ei = e_s [base + i];
        int   mk = mrow[k];
        if (mk != 0) {
            Z += ei;
            float4 v = vbase[(size_t)k * (ND / 4) + lane];
            acc.x += ei * v.x; acc.y += ei * v.y;
            acc.z += ei * v.z; acc.w += ei * v.w;
        }
        // break is exact when rem==0; otherwise remaining mass <= 1e-6*Z
        if (rem[base + i] <= 1e-6f * Z) break;
    }

    float4* orow = (float4*)(out + (size_t)row * ND);
    if (Z > 0.0f) {
        float inv = 1.0f / Z;
        orow[lane] = make_float4(acc.x * inv, acc.y * inv, acc.z * inv, acc.w * inv);
    } else {
        // all-masked row: reference softmax over constant -1e9 -> uniform
        float4 s = make_float4(0.f, 0.f, 0.f, 0.f);
        for (int k = 0; k < NL; ++k) {
            float4 v = vbase[(size_t)k * (ND / 4) + lane];
            s.x += v.x; s.y += v.y; s.z += v.z; s.w += v.w;
        }
        const float inv = 1.0f / (float)NL;
        orow[lane] = make_float4(s.x * inv, s.y * inv, s.z * inv, s.w * inv);
    }
}

extern "C" void kernel_launch(void* const* d_in, const int* in_sizes, int n_in,
                              void* d_out, int out_size, void* d_ws, size_t ws_size,
                              hipStream_t stream) {
    // setup_inputs order: query, key, value, w, mask   (query unused!)
    const float* key   = (const float*)d_in[1];
    const float* value = (const float*)d_in[2];
    const float* w     = (const float*)d_in[3];
    const int*   mask  = (const int*)d_in[4];
    float*       outp  = (float*)d_out;

    float* ks    = (float*)d_ws;                 // 16*1024 f32
    float* e_s   = ks + NB * NL;                 // 16*1024 f32 (sorted desc)
    int*   idx_s = (int*)(e_s + NB * NL);        // 16*1024 i32
    float* rem   = (float*)(idx_s + NB * NL);    // 16*1024 f32 suffix sums

    ks_kernel  <<<NB * NL / 4, 256, 0, stream>>>(key, w, ks);
    sort_kernel<<<NB, 1024, 0, stream>>>(ks, e_s, idx_s, rem);
    attn_kernel<<<NB * NL / 4, 256, 0, stream>>>(value, mask, e_s, idx_s, rem, outp);
}

// Round 2
// 204.105 us; speedup vs baseline: 1.4847x; 1.4847x over previous
//
#include <hip/hip_runtime.h>
#include <math.h>

// Problem: B=16, LQ=1024, LK=1024, DK=256, DV=256, fp32 in/out, mask int32.
// Identity: softmax_k(q_s + k_s with mask) == mask-weighted softmax of k_s alone
// (q_s cancels; masked entries are exactly -1e9 -> weight 0). query never read.
// k_s ~ N(0,256) => softmax mass concentrates in top ~30-60 keys; walk sorted-e
// list in 64-wide chunks until provable remaining mass <= 1e-5 * Z.

#define NB     16
#define NL     1024     // LQ == LK
#define ND     256      // DK == DV
#define NSTAGE 56       // top-K value rows staged in LDS (56 KB)

// ---------------- Kernel A: ks[b,k] = dot(key[b,k,:], w) -----------------
__global__ __launch_bounds__(256)
void ks_kernel(const float* __restrict__ key, const float* __restrict__ w,
               float* __restrict__ ks) {
    int wid  = threadIdx.x >> 6;
    int lane = threadIdx.x & 63;
    int row  = blockIdx.x * 4 + wid;               // 0 .. NB*NL-1
    const float4* krow = (const float4*)(key + (size_t)row * ND);
    float4 kv = krow[lane];
    float4 wv = ((const float4*)w)[lane];
    float p = kv.x * wv.x + kv.y * wv.y + kv.z * wv.z + kv.w * wv.w;
    #pragma unroll
    for (int off = 32; off > 0; off >>= 1)
        p += __shfl_xor(p, off, 64);
    if (lane == 0) ks[row] = p;
}

// ------- Kernel B: per batch: max, e=exp(ks-m), bitonic sort desc, -------
// ------- suffix sums rem[i] = sum_{j>i} e_sorted[j]                -------
__global__ __launch_bounds__(1024)
void sort_kernel(const float* __restrict__ ks,
                 float* __restrict__ e_s, int* __restrict__ idx_s,
                 float* __restrict__ rem) {
    __shared__ float sv[NL];
    __shared__ int   si[NL];
    __shared__ float red[NL];
    int b = blockIdx.x;
    int t = threadIdx.x;

    float v = ks[b * NL + t];
    red[t] = v;
    __syncthreads();
    for (int off = 512; off > 0; off >>= 1) {
        if (t < off) red[t] = fmaxf(red[t], red[t + off]);
        __syncthreads();
    }
    float m = red[0];
    __syncthreads();

    float e = __expf(v - m);        // e in (0,1]
    sv[t] = e;
    si[t] = t;
    __syncthreads();

    // bitonic sort, descending by sv
    for (int kk = 2; kk <= NL; kk <<= 1) {
        for (int j = kk >> 1; j > 0; j >>= 1) {
            int ixj = t ^ j;
            if (ixj > t) {
                bool up = ((t & kk) == 0);
                float a = sv[t], c = sv[ixj];
                bool sw = up ? (a < c) : (a > c);
                if (sw) {
                    int ia = si[t];
                    sv[t] = c;  sv[ixj] = a;
                    si[t] = si[ixj]; si[ixj] = ia;
                }
            }
            __syncthreads();
        }
    }

    // inclusive suffix sum (Hillis-Steele), then rem = rs - self
    red[t] = sv[t];
    __syncthreads();
    for (int off = 1; off < NL; off <<= 1) {
        float add = (t + off < NL) ? red[t + off] : 0.0f;
        __syncthreads();
        red[t] += add;
        __syncthreads();
    }
    e_s  [b * NL + t] = sv[t];
    idx_s[b * NL + t] = si[t];
    rem  [b * NL + t] = red[t] - sv[t];
}

// ---------------- Kernel C: out[b,q,:] = sum_k p * value[b,k,:] ----------
// Block = 1024 threads = 16 waves = 16 q-rows (same batch). LDS stages the
// top-NSTAGE value rows + per-row mask bitmask + top-64 (e,idx). Chunked
// walk: 64 entries per chunk, break checked once per chunk via rem[] --
// processing extra entries past the exact break point only adds accuracy.
__global__ __launch_bounds__(1024)
void attn_kernel(const float* __restrict__ value, const int* __restrict__ mask,
                 const float* __restrict__ e_s, const int* __restrict__ idx_s,
                 const float* __restrict__ rem, float* __restrict__ out) {
    __shared__ float          lds_V[NSTAGE * ND];   // 56 KB
    __shared__ unsigned short mbits[16][64];        // 2 KB: 1024 mask bits/row
    __shared__ float          lds_e[64];
    __shared__ int            lds_idx[64];

    const int wid  = threadIdx.x >> 6;
    const int lane = threadIdx.x & 63;
    const int row  = blockIdx.x * 16 + wid;   // 0 .. NB*NL-1 (16 rows, same b)
    const int b    = row >> 10;
    const int base = b << 10;

    if (threadIdx.x < 64) {
        lds_e[threadIdx.x]   = e_s[base + threadIdx.x];
        lds_idx[threadIdx.x] = idx_s[base + threadIdx.x];
    }
    __syncthreads();

    const float4* vbase = (const float4*)(value + ((size_t)b << 10) * ND);

    // stage top-NSTAGE value rows (coalesced 1 KB per wave-row)
    for (int r = wid; r < NSTAGE; r += 16)
        ((float4*)lds_V)[r * 64 + lane] = vbase[(size_t)lds_idx[r] * 64 + lane];

    // mask row -> bits: lane owns ints [lane*16, lane*16+16)
    const int4* mrow4 = (const int4*)(mask + (size_t)row * NL);
    unsigned int bits = 0;
    #pragma unroll
    for (int j = 0; j < 4; ++j) {
        int4 m = mrow4[lane * 4 + j];
        bits |= (m.x != 0 ? 1u : 0u) << (j * 4 + 0);
        bits |= (m.y != 0 ? 1u : 0u) << (j * 4 + 1);
        bits |= (m.z != 0 ? 1u : 0u) << (j * 4 + 2);
        bits |= (m.w != 0 ? 1u : 0u) << (j * 4 + 3);
    }
    mbits[wid][lane] = (unsigned short)bits;
    __syncthreads();

    float4 acc = make_float4(0.f, 0.f, 0.f, 0.f);
    float Z = 0.0f;

    // chunk 0: entries [0,64), V from LDS for i < NSTAGE
    #pragma unroll 8
    for (int i = 0; i < 64; ++i) {
        int k = lds_idx[i];
        if ((mbits[wid][k >> 4] >> (k & 15)) & 1) {
            float ei = lds_e[i];
            Z += ei;
            float4 v;
            if (i < NSTAGE) v = ((const float4*)lds_V)[i * 64 + lane];
            else            v = vbase[(size_t)k * 64 + lane];
            acc.x += ei * v.x; acc.y += ei * v.y;
            acc.z += ei * v.z; acc.w += ei * v.w;
        }
    }
    bool done = (rem[base + 63] <= 1e-5f * Z);   // Z==0 -> rem>0 -> continue

    // chunks 1..15 (rare): lane-staged entries broadcast via shuffle
    for (int c = 1; c < 16 && !done; ++c) {
        const int o = base + c * 64;
        float e_r = e_s[o + lane];
        int   k_r = idx_s[o + lane];
        #pragma unroll 8
        for (int i = 0; i < 64; ++i) {
            int k = __shfl(k_r, i);
            if ((mbits[wid][k >> 4] >> (k & 15)) & 1) {
                float ei = __shfl(e_r, i);
                Z += ei;
                float4 v = vbase[(size_t)k * 64 + lane];
                acc.x += ei * v.x; acc.y += ei * v.y;
                acc.z += ei * v.z; acc.w += ei * v.w;
            }
        }
        done = (rem[o + 63] <= 1e-5f * Z);
    }

    float4* orow = (float4*)(out + (size_t)row * ND);
    if (Z > 0.0f) {
        float inv = 1.0f / Z;
        orow[lane] = make_float4(acc.x * inv, acc.y * inv, acc.z * inv, acc.w * inv);
    } else {
        // all-masked row: reference softmax over constant -1e9 -> uniform avg
        float4 s = make_float4(0.f, 0.f, 0.f, 0.f);
        for (int k = 0; k < NL; ++k) {
            float4 v = vbase[(size_t)k * 64 + lane];
            s.x += v.x; s.y += v.y; s.z += v.z; s.w += v.w;
        }
        const float inv = 1.0f / (float)NL;
        orow[lane] = make_float4(s.x * inv, s.y * inv, s.z * inv, s.w * inv);
    }
}

extern "C" void kernel_launch(void* const* d_in, const int* in_sizes, int n_in,
                              void* d_out, int out_size, void* d_ws, size_t ws_size,
                              hipStream_t stream) {
    // setup_inputs order: query, key, value, w, mask   (query unused!)
    const float* key   = (const float*)d_in[1];
    const float* value = (const float*)d_in[2];
    const float* w     = (const float*)d_in[3];
    const int*   mask  = (const int*)d_in[4];
    float*       outp  = (float*)d_out;

    float* ks    = (float*)d_ws;                 // 16*1024 f32
    float* e_s   = ks + NB * NL;                 // 16*1024 f32 (sorted desc)
    int*   idx_s = (int*)(e_s + NB * NL);        // 16*1024 i32
    float* rem   = (float*)(idx_s + NB * NL);    // 16*1024 f32 suffix sums

    ks_kernel  <<<NB * NL / 4, 256, 0, stream>>>(key, w, ks);
    sort_kernel<<<NB, 1024, 0, stream>>>(ks, e_s, idx_s, rem);
    attn_kernel<<<NB * NL / 16, 1024, 0, stream>>>(value, mask, e_s, idx_s, rem, outp);
}